// Round 9
// baseline (312.059 us; speedup 1.0000x reference)
//
#include <hip/hip_runtime.h>
#include <hip/hip_bf16.h>

#define BB 16
#define NN 1024
#define DD 5
#define RH 8

typedef unsigned long long u64;
typedef unsigned int u32;
typedef __hip_bfloat16 bf16;

static __device__ __forceinline__ float tof(bf16 x) { return __bfloat162float(x); }
// runtime-dtype load: f32 storage if f==true else bf16
static __device__ __forceinline__ float ldf(const void* p, long long i, bool f) {
  return f ? ((const float*)p)[i] : tof(((const bf16*)p)[i]);
}

#define LOG2E 1.4426950408889634f

// ---------------------------------------------------------------- pack
// adjbits[(b*N+i)*16 + w] = 64 adjacency bits. Storage mode probed per-block
// over the first 4096 words (same data + same rule every block => consistent).
// Block 0 also zero-inits the pooled accumulator + done counter used by
// k_attn (stream order guarantees completion before k_attn starts).
__global__ __launch_bounds__(256) void k_pack(const void* __restrict__ adj,
                                              u64* __restrict__ adjbits,
                                              float* __restrict__ pooled,
                                              int* __restrict__ doneCnt) {
  __shared__ int sNon01, sNonpair, sLow3;
  int tid = threadIdx.x;
  if (blockIdx.x == 0) {
    if (tid < BB * DD) pooled[tid] = 0.0f;
    if (tid == 0) *doneCnt = 0;
  }
  if (tid == 0) { sNon01 = 0; sNonpair = 0; sLow3 = 0; }
  __syncthreads();
  {
    const u32* aw = (const u32*)adj;
    int non01 = 0, nonpair = 0, low3 = 0;
    for (int i = tid; i < 4096; i += 256) {
      u32 x = aw[i];
      u32 lo = x & 0xFFFFu, hi = x >> 16;
      non01 |= (x > 1u);
      nonpair |= !((lo == 0u || lo == 0x3F80u) && (hi == 0u || hi == 0x3F80u));
      low3 |= (lo == 0x3F80u);
    }
    if (non01) atomicOr(&sNon01, 1);
    if (nonpair) atomicOr(&sNonpair, 1);
    if (low3) atomicOr(&sLow3, 1);
  }
  __syncthreads();
  // mode: 0=int32, 1=byte, 2=bf16, 3=f32
  int mode;
  if (!sNon01) mode = 0;
  else if (!sNonpair) mode = sLow3 ? 2 : 3;
  else mode = 1;

  int gid = blockIdx.x * 256 + tid;
  if (gid >= BB * NN * 16) return;
  int w = gid & 15;
  long long row = gid >> 4;
  long long base = row * NN + (long long)w * 64;
  u64 bits = 0;
  if (mode == 3) {
    const uint4* p = (const uint4*)((const float*)adj + base);
    #pragma unroll
    for (int t = 0; t < 16; ++t) {
      uint4 x = p[t];
      if (x.x << 1) bits |= 1ull << (4 * t + 0);   // ignore -0.0
      if (x.y << 1) bits |= 1ull << (4 * t + 1);
      if (x.z << 1) bits |= 1ull << (4 * t + 2);
      if (x.w << 1) bits |= 1ull << (4 * t + 3);
    }
  } else if (mode == 0) {
    const uint4* p = (const uint4*)((const u32*)adj + base);
    #pragma unroll
    for (int t = 0; t < 16; ++t) {
      uint4 x = p[t];
      if (x.x) bits |= 1ull << (4 * t + 0);
      if (x.y) bits |= 1ull << (4 * t + 1);
      if (x.z) bits |= 1ull << (4 * t + 2);
      if (x.w) bits |= 1ull << (4 * t + 3);
    }
  } else if (mode == 2) {
    const uint4* p = (const uint4*)((const unsigned short*)adj + base);
    #pragma unroll
    for (int t = 0; t < 8; ++t) {
      uint4 x = p[t];
      u32 c[4] = {x.x, x.y, x.z, x.w};
      #pragma unroll
      for (int q = 0; q < 4; ++q) {
        if ((c[q] & 0x7FFFu)) bits |= 1ull << (8 * t + 2 * q + 0);
        if ((c[q] >> 16) & 0x7FFFu) bits |= 1ull << (8 * t + 2 * q + 1);
      }
    }
  } else {
    const uint4* p = (const uint4*)((const unsigned char*)adj + base);
    #pragma unroll
    for (int t = 0; t < 4; ++t) {
      uint4 x = p[t];
      u32 c[4] = {x.x, x.y, x.z, x.w};
      #pragma unroll
      for (int q = 0; q < 4; ++q)
        #pragma unroll
        for (int bb = 0; bb < 4; ++bb)
          if ((c[q] >> (8 * bb)) & 0xFFu) bits |= 1ull << (16 * t + 4 * q + bb);
    }
  }
  adjbits[gid] = bits;
}

// -------------------------------------------------------------- two-hop
__global__ __launch_bounds__(256) void k_twohop(const u64* __restrict__ adjbits,
                                                u64* __restrict__ neighbits) {
  __shared__ unsigned short listL[4][NN];
  int wave = threadIdx.x >> 6, lane = threadIdx.x & 63;
  int row = blockIdx.x * 4 + wave;
  int b = row >> 10;
  int i = row & (NN - 1);
  int w = lane & 15;
  const u64* rowp = adjbits + (size_t)row * 16;
  u64 rw = rowp[w];
  unsigned short* list = listL[wave];
  int cnt = 0;
  #pragma unroll
  for (int sw = 0; sw < 16; ++sw) {
    u64 bits = __shfl(rw, sw, 64);
    int mybit = (int)((bits >> lane) & 1ull);
    int pre = __popcll(bits & ((1ull << lane) - 1ull));
    if (mybit) list[cnt + pre] = (unsigned short)(sw * 64 + lane);
    cnt += __popcll(bits);
  }
  __syncthreads();
  u64 acc = rw;
  if (w == (i >> 6)) acc |= 1ull << (i & 63);
  int g = lane >> 4;
  const u64* basep = adjbits + (size_t)b * NN * 16;
  for (int n = g; n < cnt; n += 4) {
    int j = list[n];
    acc |= basep[(size_t)j * 16 + w];
  }
  acc |= __shfl_xor(acc, 16, 64);
  acc |= __shfl_xor(acc, 32, 64);
  if (lane < 16) neighbits[(size_t)row * 16 + lane] = acc;
}

// ------------------------------------------------------------- attention
// Block = (b, chunk of 16 rows). Full j-sweep via two sequentially staged
// 512-node LDS tiles (30 KB). 4 waves x 4 rows. Neighbor masks preloaded and
// lane-transposed into 16-bit registers (no in-loop global loads). Direct
// exp2 with log2e folded into q/C/br2. Each block finishes complete rows ->
// atomicAdds its pooled partial; the LAST block (device-scope counter) runs
// the tiny MLP head. NO min-waves launch_bounds arg (r6/r7 spill lesson).
__global__ __launch_bounds__(256) void k_attn(
    const void* __restrict__ feats, const void* __restrict__ coors,
    const void* __restrict__ Wq, const void* __restrict__ Wk,
    const void* __restrict__ Wv, const void* __restrict__ Wo,
    const void* __restrict__ wr1, const void* __restrict__ br1,
    const void* __restrict__ wr2, const void* __restrict__ br2,
    const u64* __restrict__ neighbits, float* __restrict__ pooled,
    int* __restrict__ doneCnt,
    const void* __restrict__ w1v, const void* __restrict__ b1v,
    const void* __restrict__ w2v, const void* __restrict__ b2v,
    float* __restrict__ out) {
  __shared__ __align__(16) float4 kvL[512 * 3];  // 24 KB: k0..k4,v0..v4,pad,pad
  __shared__ float coL[512 * 3];                 // 6 KB
  __shared__ float wqL[25], wkL[25], wvL[25], woL[25];
  __shared__ float qL[16 * DD], ciL[16 * 3];
  __shared__ float wrL[3][RH];
  __shared__ float sConst[2];  // [0]=C', [1]=br2'  (log2e-folded when fast)
  __shared__ int sFast, sDone;
  __shared__ int sCnt[4];
  int b = blockIdx.x >> 6, chunk = blockIdx.x & 63;
  int tid = threadIdx.x;
  // ---- per-block feats dtype probe (256 words, ballot majority) ----
  {
    u32 x = ((const u32*)feats)[tid];
    u32 lo = x & 0xFFFFu;
    int e = (int)((lo >> 7) & 0xFFu);
    bool insane = !(lo == 0u || (e >= 90 && e <= 150));
    u64 m = __ballot(insane);
    if ((tid & 63) == 0) sCnt[tid >> 6] = (int)__popcll(m);
  }
  __syncthreads();
  bool f32 = (sCnt[0] + sCnt[1] + sCnt[2] + sCnt[3]) > 64;
  if (tid < 25) {
    wqL[tid] = ldf(Wq, tid, f32);
    wkL[tid] = ldf(Wk, tid, f32);
    wvL[tid] = ldf(Wv, tid, f32);
    woL[tid] = ldf(Wo, tid, f32);
  }
  if (tid >= 64 && tid < 64 + RH) {
    int h = tid - 64;
    wrL[0][h] = ldf(wr1, h, f32);
    wrL[1][h] = ldf(br1, h, f32);
    wrL[2][h] = ldf(wr2, h, f32);
  }
  if (tid == 96) {
    float c = 0.0f;
    int ok = 1;
    #pragma unroll
    for (int h = 0; h < RH; ++h) {
      float w1h = ldf(wr1, h, f32);
      if (ldf(br1, h, f32) != 0.0f) ok = 0;
      if (w1h > 0.0f) c += w1h * ldf(wr2, h, f32);
    }
    sConst[0] = c * LOG2E;
    sConst[1] = ldf(br2, 0, f32) * LOG2E;
    sFast = ok;
  }
  __syncthreads();
  int fast = sFast;
  // q (scaled by 1/sqrt(5), and log2e when fast) + ci for this chunk's rows
  if (tid < 16) {
    long long row = (long long)b * NN + chunk * 16 + tid;
    float f0 = ldf(feats, row * DD + 0, f32), f1 = ldf(feats, row * DD + 1, f32),
          f2 = ldf(feats, row * DD + 2, f32), f3 = ldf(feats, row * DD + 3, f32),
          f4 = ldf(feats, row * DD + 4, f32);
    float qsc = fast ? (0.4472135954999579f * LOG2E) : 0.4472135954999579f;
    #pragma unroll
    for (int e = 0; e < DD; ++e)
      qL[tid * DD + e] = (f0 * wqL[e] + f1 * wqL[5 + e] + f2 * wqL[10 + e] +
                          f3 * wqL[15 + e] + f4 * wqL[20 + e]) * qsc;
    #pragma unroll
    for (int c = 0; c < 3; ++c)
      ciL[tid * 3 + c] = ldf(coors, row * 3 + c, f32);
  }

  int g = tid >> 6, lane = tid & 63;
  int i0 = chunk * 16 + g * 4;
  // ---- neighbor-mask preload + lane transpose: msk[r] bit itg =
  //      bit `lane` of neighbits word (row i0+r, itg) ----
  u32 msk[4];
  {
    const u64* nb = neighbits + ((size_t)(b * NN + i0)) * 16;
    #pragma unroll
    for (int r = 0; r < 4; ++r) {
      u32 mk = 0;
      #pragma unroll
      for (int w16 = 0; w16 < 16; ++w16) {
        u64 word = nb[(size_t)r * 16 + w16];
        mk |= (u32)((word >> lane) & 1ull) << w16;
      }
      msk[r] = mk;
    }
  }
  float q[4][DD], ci[4][3], l[4], A[4][DD];
  float Cf = sConst[0], br2f = sConst[1];
  #pragma unroll
  for (int r = 0; r < 4; ++r) {
    l[r] = 0.0f;
    #pragma unroll
    for (int e = 0; e < DD; ++e) A[r][e] = 0.0f;
  }

  for (int ph = 0; ph < 2; ++ph) {
    __syncthreads();  // previous tile fully consumed (also covers qL/ciL wr)
    // stage k, v' = (f@Wv)@Wo and co for tile nodes [ph*512, ph*512+512)
    for (int n = tid; n < 512; n += 256) {
      long long node = (long long)b * NN + ph * 512 + n;
      float f0 = ldf(feats, node * DD + 0, f32), f1 = ldf(feats, node * DD + 1, f32),
            f2 = ldf(feats, node * DD + 2, f32), f3 = ldf(feats, node * DD + 3, f32),
            f4 = ldf(feats, node * DD + 4, f32);
      float k[DD], tv[DD], v[DD];
      #pragma unroll
      for (int e = 0; e < DD; ++e) {
        k[e] = f0 * wkL[e] + f1 * wkL[5 + e] + f2 * wkL[10 + e] + f3 * wkL[15 + e] +
               f4 * wkL[20 + e];
        tv[e] = f0 * wvL[e] + f1 * wvL[5 + e] + f2 * wvL[10 + e] + f3 * wvL[15 + e] +
                f4 * wvL[20 + e];
      }
      #pragma unroll
      for (int e = 0; e < DD; ++e)
        v[e] = tv[0] * woL[e] + tv[1] * woL[5 + e] + tv[2] * woL[10 + e] +
               tv[3] * woL[15 + e] + tv[4] * woL[20 + e];
      kvL[n * 3 + 0] = make_float4(k[0], k[1], k[2], k[3]);
      kvL[n * 3 + 1] = make_float4(k[4], v[0], v[1], v[2]);
      kvL[n * 3 + 2] = make_float4(v[3], v[4], 0.f, 0.f);
    }
    for (int idx = tid; idx < 512 * 3; idx += 256)
      coL[idx] = ldf(coors, ((long long)(b * NN) + ph * 512) * 3 + idx, f32);
    __syncthreads();
    if (ph == 0) {
      #pragma unroll
      for (int r = 0; r < 4; ++r) {
        #pragma unroll
        for (int e = 0; e < DD; ++e) q[r][e] = qL[(g * 4 + r) * DD + e];
        #pragma unroll
        for (int c = 0; c < 3; ++c) ci[r][c] = ciL[(g * 4 + r) * 3 + c];
      }
    }
    #pragma unroll
    for (int it = 0; it < 8; ++it) {
      int itg = ph * 8 + it;
      int j = it * 64 + lane;
      float4 ka = kvL[j * 3 + 0];
      float4 kb = kvL[j * 3 + 1];
      float4 kc = kvL[j * 3 + 2];
      float jx = coL[j * 3], jy = coL[j * 3 + 1], jz = coL[j * 3 + 2];
      if (fast) {
        #pragma unroll
        for (int r = 0; r < 4; ++r) {
          float cx = jx - ci[r][0], cy = jy - ci[r][1], cz = jz - ci[r][2];
          float dist =
              __builtin_amdgcn_sqrtf(fmaf(cx, cx, fmaf(cy, cy, fmaf(cz, cz, 1e-8f))));
          float s = fmaf(q[r][0], ka.x, br2f);
          s = fmaf(q[r][1], ka.y, s);
          s = fmaf(q[r][2], ka.z, s);
          s = fmaf(q[r][3], ka.w, s);
          s = fmaf(q[r][4], kb.x, s);
          s = fmaf(Cf, dist, s);
          s = fminf(s, 126.0f);
          s = ((msk[r] >> itg) & 1u) ? s : -150.0f;
          float p = __builtin_amdgcn_exp2f(s);
          l[r] += p;
          A[r][0] = fmaf(p, kb.y, A[r][0]);
          A[r][1] = fmaf(p, kb.z, A[r][1]);
          A[r][2] = fmaf(p, kb.w, A[r][2]);
          A[r][3] = fmaf(p, kc.x, A[r][3]);
          A[r][4] = fmaf(p, kc.y, A[r][4]);
        }
      } else {
        #pragma unroll
        for (int r = 0; r < 4; ++r) {
          float cx = jx - ci[r][0], cy = jy - ci[r][1], cz = jz - ci[r][2];
          float dist = sqrtf(fmaf(cx, cx, fmaf(cy, cy, fmaf(cz, cz, 1e-8f))));
          float rb = ldf(br2, 0, f32);
          #pragma unroll
          for (int h = 0; h < RH; ++h)
            rb += fmaxf(dist * wrL[0][h] + wrL[1][h], 0.0f) * wrL[2][h];
          float s = fmaf(q[r][0], ka.x, rb);
          s = fmaf(q[r][1], ka.y, s);
          s = fmaf(q[r][2], ka.z, s);
          s = fmaf(q[r][3], ka.w, s);
          s = fmaf(q[r][4], kb.x, s);
          s = fminf(s, 85.0f);
          s = ((msk[r] >> itg) & 1u) ? s : -100.0f;
          float p = __expf(s);
          l[r] += p;
          A[r][0] = fmaf(p, kb.y, A[r][0]);
          A[r][1] = fmaf(p, kb.z, A[r][1]);
          A[r][2] = fmaf(p, kb.w, A[r][2]);
          A[r][3] = fmaf(p, kc.x, A[r][3]);
          A[r][4] = fmaf(p, kc.y, A[r][4]);
        }
      }
    }
  }
  #pragma unroll
  for (int msk2 = 1; msk2 < 64; msk2 <<= 1) {
    #pragma unroll
    for (int r = 0; r < 4; ++r) {
      l[r] += __shfl_xor(l[r], msk2, 64);
      A[r][0] += __shfl_xor(A[r][0], msk2, 64);
      A[r][1] += __shfl_xor(A[r][1], msk2, 64);
      A[r][2] += __shfl_xor(A[r][2], msk2, 64);
      A[r][3] += __shfl_xor(A[r][3], msk2, 64);
      A[r][4] += __shfl_xor(A[r][4], msk2, 64);
    }
  }
  if (lane == 0) {
    float pe[DD] = {0.f, 0.f, 0.f, 0.f, 0.f};
    #pragma unroll
    for (int r = 0; r < 4; ++r) {
      float inv = (l[r] > 0.f) ? 1.0f / l[r] : 0.0f;
      long long base = ((long long)b * NN + i0 + r) * DD;
      #pragma unroll
      for (int e = 0; e < DD; ++e)
        pe[e] += ldf(feats, base + e, f32) + A[r][e] * inv;
    }
    #pragma unroll
    for (int e = 0; e < DD; ++e) atomicAdd(&pooled[b * DD + e], pe[e]);
  }
  // ---- last block runs the MLP head ----
  __syncthreads();
  __threadfence();
  if (tid == 0) sDone = (atomicAdd(doneCnt, 1) == (int)gridDim.x - 1);
  __syncthreads();
  if (sDone) {
    __threadfence();
    int bb2 = tid >> 4, sub = tid & 15;
    float pl[DD];
    #pragma unroll
    for (int e = 0; e < DD; ++e)
      pl[e] = pooled[bb2 * DD + e] * (1.0f / 1024.0f);
    float a0 = 0.f, a1 = 0.f, a2 = 0.f;
    for (int jj = sub * 8; jj < sub * 8 + 8; ++jj) {
      float h = ldf(b1v, jj, f32);
      #pragma unroll
      for (int d = 0; d < DD; ++d)
        h = fmaf(pl[d], ldf(w1v, d * 128 + jj, f32), h);
      h = fmaxf(h, 0.0f);
      a0 = fmaf(h, ldf(w2v, jj * 3 + 0, f32), a0);
      a1 = fmaf(h, ldf(w2v, jj * 3 + 1, f32), a1);
      a2 = fmaf(h, ldf(w2v, jj * 3 + 2, f32), a2);
    }
    #pragma unroll
    for (int mk = 1; mk < 16; mk <<= 1) {
      a0 += __shfl_xor(a0, mk, 64);
      a1 += __shfl_xor(a1, mk, 64);
      a2 += __shfl_xor(a2, mk, 64);
    }
    if (sub == 0) {
      out[bb2 * 3 + 0] = a0 + ldf(b2v, 0, f32);
      out[bb2 * 3 + 1] = a1 + ldf(b2v, 1, f32);
      out[bb2 * 3 + 2] = a2 + ldf(b2v, 2, f32);
    }
  }
}

// ---------------------------------------------------------------- launch
extern "C" void kernel_launch(void* const* d_in, const int* in_sizes, int n_in,
                              void* d_out, int out_size, void* d_ws, size_t ws_size,
                              hipStream_t stream) {
  const void* adj = d_in[2];
  float* out = (float*)d_out;

  char* w = (char*)d_ws;
  int* doneCnt = (int*)w;                       // 1 int
  float* pooled = (float*)(w + 64);             // 80 f32
  const size_t BITS_BYTES = (size_t)BB * NN * 16 * sizeof(u64);  // 2 MiB
  u64* adjbits = (u64*)(w + 512);
  u64* neighbits = (u64*)(w + 512 + BITS_BYTES);

  k_pack<<<BB * NN * 16 / 256, 256, 0, stream>>>(adj, adjbits, pooled, doneCnt);
  k_twohop<<<BB * NN / 4, 256, 0, stream>>>(adjbits, neighbits);
  k_attn<<<BB * 64, 256, 0, stream>>>(d_in[0], d_in[1], d_in[3], d_in[4], d_in[5],
                                      d_in[6], d_in[7], d_in[8], d_in[9], d_in[10],
                                      neighbits, pooled, doneCnt,
                                      d_in[11], d_in[12], d_in[13], d_in[14], out);
}

// Round 10
// 282.585 us; speedup vs baseline: 1.1043x; 1.1043x over previous
//
#include <hip/hip_runtime.h>
#include <hip/hip_bf16.h>

#define BB 16
#define NN 1024
#define DD 5
#define RH 8

typedef unsigned long long u64;
typedef unsigned int u32;
typedef __hip_bfloat16 bf16;

static __device__ __forceinline__ float tof(bf16 x) { return __bfloat162float(x); }
// runtime-dtype load: f32 storage if f==true else bf16
static __device__ __forceinline__ float ldf(const void* p, long long i, bool f) {
  return f ? ((const float*)p)[i] : tof(((const bf16*)p)[i]);
}

#define LOG2E 1.4426950408889634f

// ---------------------------------------------------------------- pack
// adjbits[(b*N+i)*16 + w] = 64 adjacency bits. Storage mode probed per-block
// over the first 4096 words. Block 0 zero-inits the pooled accumulator
// (stream order guarantees completion before k_attn).
__global__ __launch_bounds__(256) void k_pack(const void* __restrict__ adj,
                                              u64* __restrict__ adjbits,
                                              float* __restrict__ pooled) {
  __shared__ int sNon01, sNonpair, sLow3;
  int tid = threadIdx.x;
  if (blockIdx.x == 0 && tid < BB * DD) pooled[tid] = 0.0f;
  if (tid == 0) { sNon01 = 0; sNonpair = 0; sLow3 = 0; }
  __syncthreads();
  {
    const u32* aw = (const u32*)adj;
    int non01 = 0, nonpair = 0, low3 = 0;
    for (int i = tid; i < 4096; i += 256) {
      u32 x = aw[i];
      u32 lo = x & 0xFFFFu, hi = x >> 16;
      non01 |= (x > 1u);
      nonpair |= !((lo == 0u || lo == 0x3F80u) && (hi == 0u || hi == 0x3F80u));
      low3 |= (lo == 0x3F80u);
    }
    if (non01) atomicOr(&sNon01, 1);
    if (nonpair) atomicOr(&sNonpair, 1);
    if (low3) atomicOr(&sLow3, 1);
  }
  __syncthreads();
  // mode: 0=int32, 1=byte, 2=bf16, 3=f32
  int mode;
  if (!sNon01) mode = 0;
  else if (!sNonpair) mode = sLow3 ? 2 : 3;
  else mode = 1;

  int gid = blockIdx.x * 256 + tid;
  if (gid >= BB * NN * 16) return;
  int w = gid & 15;
  long long row = gid >> 4;
  long long base = row * NN + (long long)w * 64;
  u64 bits = 0;
  if (mode == 3) {
    const uint4* p = (const uint4*)((const float*)adj + base);
    #pragma unroll
    for (int t = 0; t < 16; ++t) {
      uint4 x = p[t];
      if (x.x << 1) bits |= 1ull << (4 * t + 0);   // ignore -0.0
      if (x.y << 1) bits |= 1ull << (4 * t + 1);
      if (x.z << 1) bits |= 1ull << (4 * t + 2);
      if (x.w << 1) bits |= 1ull << (4 * t + 3);
    }
  } else if (mode == 0) {
    const uint4* p = (const uint4*)((const u32*)adj + base);
    #pragma unroll
    for (int t = 0; t < 16; ++t) {
      uint4 x = p[t];
      if (x.x) bits |= 1ull << (4 * t + 0);
      if (x.y) bits |= 1ull << (4 * t + 1);
      if (x.z) bits |= 1ull << (4 * t + 2);
      if (x.w) bits |= 1ull << (4 * t + 3);
    }
  } else if (mode == 2) {
    const uint4* p = (const uint4*)((const unsigned short*)adj + base);
    #pragma unroll
    for (int t = 0; t < 8; ++t) {
      uint4 x = p[t];
      u32 c[4] = {x.x, x.y, x.z, x.w};
      #pragma unroll
      for (int q = 0; q < 4; ++q) {
        if ((c[q] & 0x7FFFu)) bits |= 1ull << (8 * t + 2 * q + 0);
        if ((c[q] >> 16) & 0x7FFFu) bits |= 1ull << (8 * t + 2 * q + 1);
      }
    }
  } else {
    const uint4* p = (const uint4*)((const unsigned char*)adj + base);
    #pragma unroll
    for (int t = 0; t < 4; ++t) {
      uint4 x = p[t];
      u32 c[4] = {x.x, x.y, x.z, x.w};
      #pragma unroll
      for (int q = 0; q < 4; ++q)
        #pragma unroll
        for (int bb = 0; bb < 4; ++bb)
          if ((c[q] >> (8 * bb)) & 0xFFu) bits |= 1ull << (16 * t + 4 * q + bb);
    }
  }
  adjbits[gid] = bits;
}

// -------------------------------------------------------------- two-hop
__global__ __launch_bounds__(256) void k_twohop(const u64* __restrict__ adjbits,
                                                u64* __restrict__ neighbits) {
  __shared__ unsigned short listL[4][NN];
  int wave = threadIdx.x >> 6, lane = threadIdx.x & 63;
  int row = blockIdx.x * 4 + wave;
  int b = row >> 10;
  int i = row & (NN - 1);
  int w = lane & 15;
  const u64* rowp = adjbits + (size_t)row * 16;
  u64 rw = rowp[w];
  unsigned short* list = listL[wave];
  int cnt = 0;
  #pragma unroll
  for (int sw = 0; sw < 16; ++sw) {
    u64 bits = __shfl(rw, sw, 64);
    int mybit = (int)((bits >> lane) & 1ull);
    int pre = __popcll(bits & ((1ull << lane) - 1ull));
    if (mybit) list[cnt + pre] = (unsigned short)(sw * 64 + lane);
    cnt += __popcll(bits);
  }
  __syncthreads();
  u64 acc = rw;
  if (w == (i >> 6)) acc |= 1ull << (i & 63);
  int g = lane >> 4;
  const u64* basep = adjbits + (size_t)b * NN * 16;
  for (int n = g; n < cnt; n += 4) {
    int j = list[n];
    acc |= basep[(size_t)j * 16 + w];
  }
  acc |= __shfl_xor(acc, 16, 64);
  acc |= __shfl_xor(acc, 32, 64);
  if (lane < 16) neighbits[(size_t)row * 16 + lane] = acc;
}

// ------------------------------------------------------------- attention
// Block = (b, chunk of 16 rows). Full j-sweep via two sequentially staged
// 512-node LDS tiles (~27 KB). 4 waves x 4 rows. Neighbor masks preloaded
// and lane-transposed into u32 registers (zero in-loop global loads).
// Direct exp2 with log2e folded into q/C/br2. LDS record packs coords:
// [k0..k3 | k4,v0..v2 | v3,v4,cx,cy] + cz[512] -> 4 LDS reads per j.
// NO min-waves launch_bounds (r6/r7 spill lesson); NO per-block
// __threadfence tail (r9: 262k device fences serialized L2 -> 213 us).
__global__ __launch_bounds__(256) void k_attn(
    const void* __restrict__ feats, const void* __restrict__ coors,
    const void* __restrict__ Wq, const void* __restrict__ Wk,
    const void* __restrict__ Wv, const void* __restrict__ Wo,
    const void* __restrict__ wr1, const void* __restrict__ br1,
    const void* __restrict__ wr2, const void* __restrict__ br2,
    const u64* __restrict__ neighbits, float* __restrict__ pooled) {
  __shared__ __align__(16) float4 kvL[512 * 3];  // 24 KB
  __shared__ float czL[512];                     // 2 KB
  __shared__ float wqL[25], wkL[25], wvL[25], woL[25];
  __shared__ float qL[16 * DD], ciL[16 * 3];
  __shared__ float wrL[3][RH];
  __shared__ float sConst[2];  // [0]=C', [1]=br2' (log2e-folded when fast)
  __shared__ int sFast;
  __shared__ int sCnt[4];
  int b = blockIdx.x >> 6, chunk = blockIdx.x & 63;
  int tid = threadIdx.x;
  // ---- per-block feats dtype probe (256 words, ballot majority) ----
  {
    u32 x = ((const u32*)feats)[tid];
    u32 lo = x & 0xFFFFu;
    int e = (int)((lo >> 7) & 0xFFu);
    bool insane = !(lo == 0u || (e >= 90 && e <= 150));
    u64 m = __ballot(insane);
    if ((tid & 63) == 0) sCnt[tid >> 6] = (int)__popcll(m);
  }
  __syncthreads();
  bool f32 = (sCnt[0] + sCnt[1] + sCnt[2] + sCnt[3]) > 64;
  if (tid < 25) {
    wqL[tid] = ldf(Wq, tid, f32);
    wkL[tid] = ldf(Wk, tid, f32);
    wvL[tid] = ldf(Wv, tid, f32);
    woL[tid] = ldf(Wo, tid, f32);
  }
  if (tid >= 64 && tid < 64 + RH) {
    int h = tid - 64;
    wrL[0][h] = ldf(wr1, h, f32);
    wrL[1][h] = ldf(br1, h, f32);
    wrL[2][h] = ldf(wr2, h, f32);
  }
  if (tid == 96) {
    float c = 0.0f;
    int ok = 1;
    #pragma unroll
    for (int h = 0; h < RH; ++h) {
      float w1h = ldf(wr1, h, f32);
      if (ldf(br1, h, f32) != 0.0f) ok = 0;
      if (w1h > 0.0f) c += w1h * ldf(wr2, h, f32);
    }
    sConst[0] = c * LOG2E;
    sConst[1] = ldf(br2, 0, f32) * LOG2E;
    sFast = ok;
  }
  __syncthreads();
  int fast = sFast;
  // q (scaled by 1/sqrt(5), and log2e when fast) + ci for this chunk's rows
  if (tid < 16) {
    long long row = (long long)b * NN + chunk * 16 + tid;
    float f0 = ldf(feats, row * DD + 0, f32), f1 = ldf(feats, row * DD + 1, f32),
          f2 = ldf(feats, row * DD + 2, f32), f3 = ldf(feats, row * DD + 3, f32),
          f4 = ldf(feats, row * DD + 4, f32);
    float qsc = fast ? (0.4472135954999579f * LOG2E) : 0.4472135954999579f;
    #pragma unroll
    for (int e = 0; e < DD; ++e)
      qL[tid * DD + e] = (f0 * wqL[e] + f1 * wqL[5 + e] + f2 * wqL[10 + e] +
                          f3 * wqL[15 + e] + f4 * wqL[20 + e]) * qsc;
    #pragma unroll
    for (int c = 0; c < 3; ++c)
      ciL[tid * 3 + c] = ldf(coors, row * 3 + c, f32);
  }

  int g = tid >> 6, lane = tid & 63;
  int i0 = chunk * 16 + g * 4;
  // ---- neighbor-mask preload + lane transpose: msk[r] bit itg =
  //      bit `lane` of neighbits word (row i0+r, itg) ----
  u32 msk[4];
  {
    const u64* nb = neighbits + ((size_t)(b * NN + i0)) * 16;
    #pragma unroll
    for (int r = 0; r < 4; ++r) {
      u32 mk = 0;
      #pragma unroll
      for (int w16 = 0; w16 < 16; ++w16) {
        u64 word = nb[(size_t)r * 16 + w16];
        mk |= (u32)((word >> lane) & 1ull) << w16;
      }
      msk[r] = mk;
    }
  }
  float q[4][DD], ci[4][3], l[4], A[4][DD];
  float Cf = sConst[0], br2f = sConst[1];
  #pragma unroll
  for (int r = 0; r < 4; ++r) {
    l[r] = 0.0f;
    #pragma unroll
    for (int e = 0; e < DD; ++e) A[r][e] = 0.0f;
  }

  for (int ph = 0; ph < 2; ++ph) {
    __syncthreads();  // previous tile fully consumed (also covers qL/ciL wr)
    // stage k, v' = (f@Wv)@Wo, co for tile nodes [ph*512, ph*512+512)
    for (int n = tid; n < 512; n += 256) {
      long long node = (long long)b * NN + ph * 512 + n;
      float f0 = ldf(feats, node * DD + 0, f32), f1 = ldf(feats, node * DD + 1, f32),
            f2 = ldf(feats, node * DD + 2, f32), f3 = ldf(feats, node * DD + 3, f32),
            f4 = ldf(feats, node * DD + 4, f32);
      float k[DD], tv[DD], v[DD];
      #pragma unroll
      for (int e = 0; e < DD; ++e) {
        k[e] = f0 * wkL[e] + f1 * wkL[5 + e] + f2 * wkL[10 + e] + f3 * wkL[15 + e] +
               f4 * wkL[20 + e];
        tv[e] = f0 * wvL[e] + f1 * wvL[5 + e] + f2 * wvL[10 + e] + f3 * wvL[15 + e] +
                f4 * wvL[20 + e];
      }
      #pragma unroll
      for (int e = 0; e < DD; ++e)
        v[e] = tv[0] * woL[e] + tv[1] * woL[5 + e] + tv[2] * woL[10 + e] +
               tv[3] * woL[15 + e] + tv[4] * woL[20 + e];
      float cx = ldf(coors, node * 3 + 0, f32);
      float cy = ldf(coors, node * 3 + 1, f32);
      float cz = ldf(coors, node * 3 + 2, f32);
      kvL[n * 3 + 0] = make_float4(k[0], k[1], k[2], k[3]);
      kvL[n * 3 + 1] = make_float4(k[4], v[0], v[1], v[2]);
      kvL[n * 3 + 2] = make_float4(v[3], v[4], cx, cy);
      czL[n] = cz;
    }
    __syncthreads();
    if (ph == 0) {
      #pragma unroll
      for (int r = 0; r < 4; ++r) {
        #pragma unroll
        for (int e = 0; e < DD; ++e) q[r][e] = qL[(g * 4 + r) * DD + e];
        #pragma unroll
        for (int c = 0; c < 3; ++c) ci[r][c] = ciL[(g * 4 + r) * 3 + c];
      }
    }
    #pragma unroll
    for (int it = 0; it < 8; ++it) {
      int itg = ph * 8 + it;
      int j = it * 64 + lane;
      float4 ka = kvL[j * 3 + 0];
      float4 kb = kvL[j * 3 + 1];
      float4 kc = kvL[j * 3 + 2];
      float jx = kc.z, jy = kc.w, jz = czL[j];
      if (fast) {
        #pragma unroll
        for (int r = 0; r < 4; ++r) {
          float cx = jx - ci[r][0], cy = jy - ci[r][1], cz = jz - ci[r][2];
          float dist =
              __builtin_amdgcn_sqrtf(fmaf(cx, cx, fmaf(cy, cy, fmaf(cz, cz, 1e-8f))));
          float s = fmaf(q[r][0], ka.x, br2f);
          s = fmaf(q[r][1], ka.y, s);
          s = fmaf(q[r][2], ka.z, s);
          s = fmaf(q[r][3], ka.w, s);
          s = fmaf(q[r][4], kb.x, s);
          s = fmaf(Cf, dist, s);
          s = fminf(s, 126.0f);
          s = ((msk[r] >> itg) & 1u) ? s : -150.0f;
          float p = __builtin_amdgcn_exp2f(s);
          l[r] += p;
          A[r][0] = fmaf(p, kb.y, A[r][0]);
          A[r][1] = fmaf(p, kb.z, A[r][1]);
          A[r][2] = fmaf(p, kb.w, A[r][2]);
          A[r][3] = fmaf(p, kc.x, A[r][3]);
          A[r][4] = fmaf(p, kc.y, A[r][4]);
        }
      } else {
        #pragma unroll
        for (int r = 0; r < 4; ++r) {
          float cx = jx - ci[r][0], cy = jy - ci[r][1], cz = jz - ci[r][2];
          float dist = sqrtf(fmaf(cx, cx, fmaf(cy, cy, fmaf(cz, cz, 1e-8f))));
          float rb = ldf(br2, 0, f32);
          #pragma unroll
          for (int h = 0; h < RH; ++h)
            rb += fmaxf(dist * wrL[0][h] + wrL[1][h], 0.0f) * wrL[2][h];
          float s = fmaf(q[r][0], ka.x, rb);
          s = fmaf(q[r][1], ka.y, s);
          s = fmaf(q[r][2], ka.z, s);
          s = fmaf(q[r][3], ka.w, s);
          s = fmaf(q[r][4], kb.x, s);
          s = fminf(s, 85.0f);
          s = ((msk[r] >> itg) & 1u) ? s : -100.0f;
          float p = __expf(s);
          l[r] += p;
          A[r][0] = fmaf(p, kb.y, A[r][0]);
          A[r][1] = fmaf(p, kb.z, A[r][1]);
          A[r][2] = fmaf(p, kb.w, A[r][2]);
          A[r][3] = fmaf(p, kc.x, A[r][3]);
          A[r][4] = fmaf(p, kc.y, A[r][4]);
        }
      }
    }
  }
  #pragma unroll
  for (int mk2 = 1; mk2 < 64; mk2 <<= 1) {
    #pragma unroll
    for (int r = 0; r < 4; ++r) {
      l[r] += __shfl_xor(l[r], mk2, 64);
      A[r][0] += __shfl_xor(A[r][0], mk2, 64);
      A[r][1] += __shfl_xor(A[r][1], mk2, 64);
      A[r][2] += __shfl_xor(A[r][2], mk2, 64);
      A[r][3] += __shfl_xor(A[r][3], mk2, 64);
      A[r][4] += __shfl_xor(A[r][4], mk2, 64);
    }
  }
  if (lane == 0) {
    float pe[DD] = {0.f, 0.f, 0.f, 0.f, 0.f};
    #pragma unroll
    for (int r = 0; r < 4; ++r) {
      float inv = (l[r] > 0.f) ? 1.0f / l[r] : 0.0f;
      long long base = ((long long)b * NN + i0 + r) * DD;
      #pragma unroll
      for (int e = 0; e < DD; ++e)
        pe[e] += ldf(feats, base + e, f32) + A[r][e] * inv;
    }
    #pragma unroll
    for (int e = 0; e < DD; ++e) atomicAdd(&pooled[b * DD + e], pe[e]);
  }
}

// ---------------------------------------------------- MLP head (1 block)
__global__ __launch_bounds__(256) void k_final(
    const void* __restrict__ feats, const float* __restrict__ pooled,
    const void* __restrict__ w1v, const void* __restrict__ b1v,
    const void* __restrict__ w2v, const void* __restrict__ b2v,
    float* __restrict__ out) {
  __shared__ int sCnt[4];
  int tid = threadIdx.x;
  {
    u32 x = ((const u32*)feats)[tid];
    u32 lo = x & 0xFFFFu;
    int e = (int)((lo >> 7) & 0xFFu);
    bool insane = !(lo == 0u || (e >= 90 && e <= 150));
    u64 m = __ballot(insane);
    if ((tid & 63) == 0) sCnt[tid >> 6] = (int)__popcll(m);
  }
  __syncthreads();
  bool f32 = (sCnt[0] + sCnt[1] + sCnt[2] + sCnt[3]) > 64;
  int b = tid >> 4, sub = tid & 15;
  float pl[DD];
  #pragma unroll
  for (int e = 0; e < DD; ++e) pl[e] = pooled[b * DD + e] * (1.0f / 1024.0f);
  float a0 = 0.f, a1 = 0.f, a2 = 0.f;
  for (int jj = sub * 8; jj < sub * 8 + 8; ++jj) {
    float h = ldf(b1v, jj, f32);
    #pragma unroll
    for (int d = 0; d < DD; ++d)
      h = fmaf(pl[d], ldf(w1v, d * 128 + jj, f32), h);
    h = fmaxf(h, 0.0f);
    a0 = fmaf(h, ldf(w2v, jj * 3 + 0, f32), a0);
    a1 = fmaf(h, ldf(w2v, jj * 3 + 1, f32), a1);
    a2 = fmaf(h, ldf(w2v, jj * 3 + 2, f32), a2);
  }
  #pragma unroll
  for (int mk = 1; mk < 16; mk <<= 1) {
    a0 += __shfl_xor(a0, mk, 64);
    a1 += __shfl_xor(a1, mk, 64);
    a2 += __shfl_xor(a2, mk, 64);
  }
  if (sub == 0) {
    out[b * 3 + 0] = a0 + ldf(b2v, 0, f32);
    out[b * 3 + 1] = a1 + ldf(b2v, 1, f32);
    out[b * 3 + 2] = a2 + ldf(b2v, 2, f32);
  }
}

// ---------------------------------------------------------------- launch
extern "C" void kernel_launch(void* const* d_in, const int* in_sizes, int n_in,
                              void* d_out, int out_size, void* d_ws, size_t ws_size,
                              hipStream_t stream) {
  const void* adj = d_in[2];
  float* out = (float*)d_out;

  char* w = (char*)d_ws;
  float* pooled = (float*)(w + 64);             // 80 f32
  const size_t BITS_BYTES = (size_t)BB * NN * 16 * sizeof(u64);  // 2 MiB
  u64* adjbits = (u64*)(w + 512);
  u64* neighbits = (u64*)(w + 512 + BITS_BYTES);

  k_pack<<<BB * NN * 16 / 256, 256, 0, stream>>>(adj, adjbits, pooled);
  k_twohop<<<BB * NN / 4, 256, 0, stream>>>(adjbits, neighbits);
  k_attn<<<BB * 64, 256, 0, stream>>>(d_in[0], d_in[1], d_in[3], d_in[4], d_in[5],
                                      d_in[6], d_in[7], d_in[8], d_in[9], d_in[10],
                                      neighbits, pooled);
  k_final<<<1, 256, 0, stream>>>(d_in[0], pooled, d_in[11], d_in[12], d_in[13],
                                 d_in[14], out);
}

// Round 11
// 190.669 us; speedup vs baseline: 1.6367x; 1.4821x over previous
//
#include <hip/hip_runtime.h>
#include <hip/hip_bf16.h>

#define BB 16
#define NN 1024
#define DD 5
#define RH 8

typedef unsigned long long u64;
typedef unsigned int u32;
typedef __hip_bfloat16 bf16;

static __device__ __forceinline__ float tof(bf16 x) { return __bfloat162float(x); }
// runtime-dtype load: f32 storage if f==true else bf16
static __device__ __forceinline__ float ldf(const void* p, long long i, bool f) {
  return f ? ((const float*)p)[i] : tof(((const bf16*)p)[i]);
}

#define LOG2E 1.4426950408889634f

// ---------------------------------------------------------------- pack
// adjbits[(b*N+i)*16 + w] = 64 adjacency bits. Storage mode probed per-block
// over the first 4096 words (same data + same rule every block => consistent).
__global__ __launch_bounds__(256) void k_pack(const void* __restrict__ adj,
                                              u64* __restrict__ adjbits) {
  __shared__ int sNon01, sNonpair, sLow3;
  int tid = threadIdx.x;
  if (tid == 0) { sNon01 = 0; sNonpair = 0; sLow3 = 0; }
  __syncthreads();
  {
    const u32* aw = (const u32*)adj;
    int non01 = 0, nonpair = 0, low3 = 0;
    for (int i = tid; i < 4096; i += 256) {
      u32 x = aw[i];
      u32 lo = x & 0xFFFFu, hi = x >> 16;
      non01 |= (x > 1u);
      nonpair |= !((lo == 0u || lo == 0x3F80u) && (hi == 0u || hi == 0x3F80u));
      low3 |= (lo == 0x3F80u);
    }
    if (non01) atomicOr(&sNon01, 1);
    if (nonpair) atomicOr(&sNonpair, 1);
    if (low3) atomicOr(&sLow3, 1);
  }
  __syncthreads();
  // mode: 0=int32, 1=byte, 2=bf16, 3=f32
  int mode;
  if (!sNon01) mode = 0;
  else if (!sNonpair) mode = sLow3 ? 2 : 3;
  else mode = 1;

  int gid = blockIdx.x * 256 + tid;
  if (gid >= BB * NN * 16) return;
  int w = gid & 15;
  long long row = gid >> 4;
  long long base = row * NN + (long long)w * 64;
  u64 bits = 0;
  if (mode == 3) {
    const uint4* p = (const uint4*)((const float*)adj + base);
    #pragma unroll
    for (int t = 0; t < 16; ++t) {
      uint4 x = p[t];
      if (x.x << 1) bits |= 1ull << (4 * t + 0);   // ignore -0.0
      if (x.y << 1) bits |= 1ull << (4 * t + 1);
      if (x.z << 1) bits |= 1ull << (4 * t + 2);
      if (x.w << 1) bits |= 1ull << (4 * t + 3);
    }
  } else if (mode == 0) {
    const uint4* p = (const uint4*)((const u32*)adj + base);
    #pragma unroll
    for (int t = 0; t < 16; ++t) {
      uint4 x = p[t];
      if (x.x) bits |= 1ull << (4 * t + 0);
      if (x.y) bits |= 1ull << (4 * t + 1);
      if (x.z) bits |= 1ull << (4 * t + 2);
      if (x.w) bits |= 1ull << (4 * t + 3);
    }
  } else if (mode == 2) {
    const uint4* p = (const uint4*)((const unsigned short*)adj + base);
    #pragma unroll
    for (int t = 0; t < 8; ++t) {
      uint4 x = p[t];
      u32 c[4] = {x.x, x.y, x.z, x.w};
      #pragma unroll
      for (int q = 0; q < 4; ++q) {
        if ((c[q] & 0x7FFFu)) bits |= 1ull << (8 * t + 2 * q + 0);
        if ((c[q] >> 16) & 0x7FFFu) bits |= 1ull << (8 * t + 2 * q + 1);
      }
    }
  } else {
    const uint4* p = (const uint4*)((const unsigned char*)adj + base);
    #pragma unroll
    for (int t = 0; t < 4; ++t) {
      uint4 x = p[t];
      u32 c[4] = {x.x, x.y, x.z, x.w};
      #pragma unroll
      for (int q = 0; q < 4; ++q)
        #pragma unroll
        for (int bb = 0; bb < 4; ++bb)
          if ((c[q] >> (8 * bb)) & 0xFFu) bits |= 1ull << (16 * t + 4 * q + bb);
    }
  }
  adjbits[gid] = bits;
}

// -------------------------------------------------------------- two-hop
__global__ __launch_bounds__(256) void k_twohop(const u64* __restrict__ adjbits,
                                                u64* __restrict__ neighbits) {
  __shared__ unsigned short listL[4][NN];
  int wave = threadIdx.x >> 6, lane = threadIdx.x & 63;
  int row = blockIdx.x * 4 + wave;
  int b = row >> 10;
  int i = row & (NN - 1);
  int w = lane & 15;
  const u64* rowp = adjbits + (size_t)row * 16;
  u64 rw = rowp[w];
  unsigned short* list = listL[wave];
  int cnt = 0;
  #pragma unroll
  for (int sw = 0; sw < 16; ++sw) {
    u64 bits = __shfl(rw, sw, 64);
    int mybit = (int)((bits >> lane) & 1ull);
    int pre = __popcll(bits & ((1ull << lane) - 1ull));
    if (mybit) list[cnt + pre] = (unsigned short)(sw * 64 + lane);
    cnt += __popcll(bits);
  }
  __syncthreads();
  u64 acc = rw;
  if (w == (i >> 6)) acc |= 1ull << (i & 63);
  int g = lane >> 4;
  const u64* basep = adjbits + (size_t)b * NN * 16;
  for (int n = g; n < cnt; n += 4) {
    int j = list[n];
    acc |= basep[(size_t)j * 16 + w];
  }
  acc |= __shfl_xor(acc, 16, 64);
  acc |= __shfl_xor(acc, 32, 64);
  if (lane < 16) neighbits[(size_t)row * 16 + lane] = acc;
}

// ------------------------------------------------------------- attention
// REVERT to the round-8 structure (proven 53 us): block = (b, chunk of 16
// rows, j-half of 512), 4 waves x 4 rows, in-loop wave-uniform mask loads,
// NO unroll pragma on the it-loop (r9's full unroll + mask-transpose
// prologue regressed 53->155 us with no memory/counter signature — giant
// straight-line body suspected). Two safe deltas only:
//  (1) exp2 with log2e folded into q/C/br2 (absmax 0.0 in r9/r10),
//      __builtin_amdgcn_sqrtf in fast path;
//  (2) packed LDS record [k0..k3|k4,v0..v2|v3,v4,cx,cy] + cz[512]:
//      6 -> 4 LDS reads/j, LDS 32.3 -> ~27 KB -> 5 blocks/CU.
__global__ __launch_bounds__(256) void k_attn(
    const void* __restrict__ feats, const void* __restrict__ coors,
    const void* __restrict__ Wq, const void* __restrict__ Wk,
    const void* __restrict__ Wv, const void* __restrict__ Wo,
    const void* __restrict__ wr1, const void* __restrict__ br1,
    const void* __restrict__ wr2, const void* __restrict__ br2,
    const u64* __restrict__ neighbits, float* __restrict__ rowAgg) {
  __shared__ __align__(16) float4 kvL[512 * 3];  // 24 KB
  __shared__ float czL[512];                     // 2 KB
  __shared__ float wqL[25], wkL[25], wvL[25], woL[25];
  __shared__ float qL[16 * DD], ciL[16 * 3];
  __shared__ float wrL[3][RH];
  __shared__ float sConst[2];  // [0]=C*log2e, [1]=br2*log2e (when fast)
  __shared__ int sFast;
  __shared__ int sCnt[4];
  int bi = blockIdx.x;
  int b = bi >> 7, rem = bi & 127, chunk = rem >> 1, half = rem & 1;
  int j0 = half * 512;
  int tid = threadIdx.x;
  // ---- per-block feats dtype probe (256 words, ballot majority) ----
  {
    u32 x = ((const u32*)feats)[tid];
    u32 lo = x & 0xFFFFu;
    int e = (int)((lo >> 7) & 0xFFu);
    bool insane = !(lo == 0u || (e >= 90 && e <= 150));
    u64 m = __ballot(insane);
    if ((tid & 63) == 0) sCnt[tid >> 6] = (int)__popcll(m);
  }
  __syncthreads();
  bool f32 = (sCnt[0] + sCnt[1] + sCnt[2] + sCnt[3]) > 64;
  if (tid < 25) {
    wqL[tid] = ldf(Wq, tid, f32);
    wkL[tid] = ldf(Wk, tid, f32);
    wvL[tid] = ldf(Wv, tid, f32);
    woL[tid] = ldf(Wo, tid, f32);
  }
  if (tid >= 64 && tid < 64 + RH) {
    int h = tid - 64;
    wrL[0][h] = ldf(wr1, h, f32);
    wrL[1][h] = ldf(br1, h, f32);
    wrL[2][h] = ldf(wr2, h, f32);
  }
  if (tid == 96) {
    float c = 0.0f;
    int ok = 1;
    #pragma unroll
    for (int h = 0; h < RH; ++h) {
      float w1h = ldf(wr1, h, f32);
      if (ldf(br1, h, f32) != 0.0f) ok = 0;
      if (w1h > 0.0f) c += w1h * ldf(wr2, h, f32);
    }
    sConst[0] = c * LOG2E;
    sConst[1] = ldf(br2, 0, f32) * LOG2E;
    sFast = ok;
  }
  __syncthreads();
  int fast = sFast;
  // stage k, v' = (f@Wv)@Wo, coords for this j-half (packed record)
  for (int n = tid; n < 512; n += 256) {
    long long node = (long long)b * NN + j0 + n;
    float f0 = ldf(feats, node * DD + 0, f32), f1 = ldf(feats, node * DD + 1, f32),
          f2 = ldf(feats, node * DD + 2, f32), f3 = ldf(feats, node * DD + 3, f32),
          f4 = ldf(feats, node * DD + 4, f32);
    float k[DD], tv[DD], v[DD];
    #pragma unroll
    for (int e = 0; e < DD; ++e) {
      k[e] = f0 * wkL[e] + f1 * wkL[5 + e] + f2 * wkL[10 + e] + f3 * wkL[15 + e] +
             f4 * wkL[20 + e];
      tv[e] = f0 * wvL[e] + f1 * wvL[5 + e] + f2 * wvL[10 + e] + f3 * wvL[15 + e] +
              f4 * wvL[20 + e];
    }
    #pragma unroll
    for (int e = 0; e < DD; ++e)
      v[e] = tv[0] * woL[e] + tv[1] * woL[5 + e] + tv[2] * woL[10 + e] +
             tv[3] * woL[15 + e] + tv[4] * woL[20 + e];
    float cx = ldf(coors, node * 3 + 0, f32);
    float cy = ldf(coors, node * 3 + 1, f32);
    float cz = ldf(coors, node * 3 + 2, f32);
    kvL[n * 3 + 0] = make_float4(k[0], k[1], k[2], k[3]);
    kvL[n * 3 + 1] = make_float4(k[4], v[0], v[1], v[2]);
    kvL[n * 3 + 2] = make_float4(v[3], v[4], cx, cy);
    czL[n] = cz;
  }
  // q (scaled by 1/sqrt(5), and log2e when fast) + ci for this chunk's rows
  if (tid < 16) {
    long long row = (long long)b * NN + chunk * 16 + tid;
    float f0 = ldf(feats, row * DD + 0, f32), f1 = ldf(feats, row * DD + 1, f32),
          f2 = ldf(feats, row * DD + 2, f32), f3 = ldf(feats, row * DD + 3, f32),
          f4 = ldf(feats, row * DD + 4, f32);
    float qsc = fast ? (0.4472135954999579f * LOG2E) : 0.4472135954999579f;
    #pragma unroll
    for (int e = 0; e < DD; ++e)
      qL[tid * DD + e] = (f0 * wqL[e] + f1 * wqL[5 + e] + f2 * wqL[10 + e] +
                          f3 * wqL[15 + e] + f4 * wqL[20 + e]) * qsc;
    #pragma unroll
    for (int c = 0; c < 3; ++c)
      ciL[tid * 3 + c] = ldf(coors, row * 3 + c, f32);
  }
  __syncthreads();

  int g = tid >> 6, lane = tid & 63;
  int i0 = chunk * 16 + g * 4;
  float q[4][DD], ci[4][3], l[4], A[4][DD];
  #pragma unroll
  for (int r = 0; r < 4; ++r) {
    #pragma unroll
    for (int e = 0; e < DD; ++e) q[r][e] = qL[(g * 4 + r) * DD + e];
    #pragma unroll
    for (int c = 0; c < 3; ++c) ci[r][c] = ciL[(g * 4 + r) * 3 + c];
    l[r] = 0.0f;
    #pragma unroll
    for (int e = 0; e < DD; ++e) A[r][e] = 0.0f;
  }
  const u64* nb = neighbits + ((size_t)(b * NN + i0)) * 16 + half * 8;
  float Cf = sConst[0], br2f = sConst[1];
  for (int it = 0; it < 8; ++it) {
    int j = it * 64 + lane;
    float4 ka = kvL[j * 3 + 0];
    float4 kb = kvL[j * 3 + 1];
    float4 kc = kvL[j * 3 + 2];
    float jx = kc.z, jy = kc.w, jz = czL[j];
    u64 nw[4];
    #pragma unroll
    for (int r = 0; r < 4; ++r) nw[r] = nb[(size_t)r * 16 + it];
    if (fast) {
      #pragma unroll
      for (int r = 0; r < 4; ++r) {
        float cx = jx - ci[r][0], cy = jy - ci[r][1], cz = jz - ci[r][2];
        float dist =
            __builtin_amdgcn_sqrtf(fmaf(cx, cx, fmaf(cy, cy, fmaf(cz, cz, 1e-8f))));
        float s = fmaf(q[r][0], ka.x, br2f);
        s = fmaf(q[r][1], ka.y, s);
        s = fmaf(q[r][2], ka.z, s);
        s = fmaf(q[r][3], ka.w, s);
        s = fmaf(q[r][4], kb.x, s);
        s = fmaf(Cf, dist, s);
        s = fminf(s, 126.0f);
        s = ((nw[r] >> lane) & 1ull) ? s : -150.0f;
        float p = __builtin_amdgcn_exp2f(s);
        l[r] += p;
        A[r][0] = fmaf(p, kb.y, A[r][0]);
        A[r][1] = fmaf(p, kb.z, A[r][1]);
        A[r][2] = fmaf(p, kb.w, A[r][2]);
        A[r][3] = fmaf(p, kc.x, A[r][3]);
        A[r][4] = fmaf(p, kc.y, A[r][4]);
      }
    } else {
      #pragma unroll
      for (int r = 0; r < 4; ++r) {
        float cx = jx - ci[r][0], cy = jy - ci[r][1], cz = jz - ci[r][2];
        float dist = sqrtf(fmaf(cx, cx, fmaf(cy, cy, fmaf(cz, cz, 1e-8f))));
        float rb = ldf(br2, 0, f32);
        #pragma unroll
        for (int h = 0; h < RH; ++h)
          rb += fmaxf(dist * wrL[0][h] + wrL[1][h], 0.0f) * wrL[2][h];
        float s = fmaf(q[r][0], ka.x, rb);
        s = fmaf(q[r][1], ka.y, s);
        s = fmaf(q[r][2], ka.z, s);
        s = fmaf(q[r][3], ka.w, s);
        s = fmaf(q[r][4], kb.x, s);
        s = fminf(s, 85.0f);
        s = ((nw[r] >> lane) & 1ull) ? s : -100.0f;
        float p = __expf(s);
        l[r] += p;
        A[r][0] = fmaf(p, kb.y, A[r][0]);
        A[r][1] = fmaf(p, kb.z, A[r][1]);
        A[r][2] = fmaf(p, kb.w, A[r][2]);
        A[r][3] = fmaf(p, kc.x, A[r][3]);
        A[r][4] = fmaf(p, kc.y, A[r][4]);
      }
    }
  }
  #pragma unroll
  for (int msk = 1; msk < 64; msk <<= 1) {
    #pragma unroll
    for (int r = 0; r < 4; ++r) {
      l[r] += __shfl_xor(l[r], msk, 64);
      A[r][0] += __shfl_xor(A[r][0], msk, 64);
      A[r][1] += __shfl_xor(A[r][1], msk, 64);
      A[r][2] += __shfl_xor(A[r][2], msk, 64);
      A[r][3] += __shfl_xor(A[r][3], msk, 64);
      A[r][4] += __shfl_xor(A[r][4], msk, 64);
    }
  }
  if (lane == 0) {
    #pragma unroll
    for (int r = 0; r < 4; ++r) {
      float* o = rowAgg + (((size_t)(b * NN + i0 + r)) * 2 + half) * 6;
      o[0] = l[r];
      o[1] = A[r][0]; o[2] = A[r][1]; o[3] = A[r][2]; o[4] = A[r][3]; o[5] = A[r][4];
    }
  }
}

// --------------------------------------------------- finalize: pool + MLP
__global__ __launch_bounds__(256) void k_final(
    const void* __restrict__ feats, const float* __restrict__ rowAgg,
    const void* __restrict__ w1, const void* __restrict__ b1,
    const void* __restrict__ w2, const void* __restrict__ b2,
    float* __restrict__ out) {
  __shared__ float waveL[4][DD];
  __shared__ float poolL[DD];
  __shared__ float hL[128];
  __shared__ int sCnt[4];
  int b = blockIdx.x, tid = threadIdx.x;
  {
    u32 x = ((const u32*)feats)[tid];
    u32 lo = x & 0xFFFFu;
    int e = (int)((lo >> 7) & 0xFFu);
    bool insane = !(lo == 0u || (e >= 90 && e <= 150));
    u64 m = __ballot(insane);
    if ((tid & 63) == 0) sCnt[tid >> 6] = (int)__popcll(m);
  }
  __syncthreads();
  bool f32 = (sCnt[0] + sCnt[1] + sCnt[2] + sCnt[3]) > 64;
  float pe[DD] = {0.f, 0.f, 0.f, 0.f, 0.f};
  for (int n = tid; n < NN; n += 256) {
    const float* ag = rowAgg + ((size_t)(b * NN + n)) * 12;
    float l = ag[0] + ag[6];
    float inv = (l > 0.f) ? 1.0f / l : 0.0f;
    long long base = ((long long)b * NN + n) * DD;
    #pragma unroll
    for (int e = 0; e < DD; ++e)
      pe[e] += ldf(feats, base + e, f32) + (ag[1 + e] + ag[7 + e]) * inv;
  }
  #pragma unroll
  for (int off = 32; off >= 1; off >>= 1)
    #pragma unroll
    for (int e = 0; e < DD; ++e) pe[e] += __shfl_down(pe[e], off, 64);
  int wave = tid >> 6, lane = tid & 63;
  if (lane == 0)
    #pragma unroll
    for (int e = 0; e < DD; ++e) waveL[wave][e] = pe[e];
  __syncthreads();
  if (tid < DD)
    poolL[tid] = (waveL[0][tid] + waveL[1][tid] + waveL[2][tid] + waveL[3][tid]) *
                 (1.0f / 1024.0f);
  __syncthreads();
  if (tid < 128) {
    float acc = ldf(b1, tid, f32);
    #pragma unroll
    for (int d = 0; d < DD; ++d)
      acc = fmaf(poolL[d], ldf(w1, d * 128 + tid, f32), acc);
    hL[tid] = fmaxf(acc, 0.0f);
  }
  __syncthreads();
  if (tid < 3) {
    float s = ldf(b2, tid, f32);
    for (int j = 0; j < 128; ++j) s = fmaf(hL[j], ldf(w2, j * 3 + tid, f32), s);
    out[b * 3 + tid] = s;
  }
}

// ---------------------------------------------------------------- launch
extern "C" void kernel_launch(void* const* d_in, const int* in_sizes, int n_in,
                              void* d_out, int out_size, void* d_ws, size_t ws_size,
                              hipStream_t stream) {
  const void* adj = d_in[2];
  float* out = (float*)d_out;

  char* w = (char*)d_ws;
  const size_t BITS_BYTES = (size_t)BB * NN * 16 * sizeof(u64);  // 2 MiB
  u64* adjbits = (u64*)(w + 512);
  u64* neighbits = (u64*)(w + 512 + BITS_BYTES);
  float* rowAgg = (float*)(w + 512 + 2 * BITS_BYTES);  // B*N*2*6 f32 = 768 KiB

  k_pack<<<BB * NN * 16 / 256, 256, 0, stream>>>(adj, adjbits);
  k_twohop<<<BB * NN / 4, 256, 0, stream>>>(adjbits, neighbits);
  k_attn<<<BB * 128, 256, 0, stream>>>(d_in[0], d_in[1], d_in[3], d_in[4], d_in[5],
                                       d_in[6], d_in[7], d_in[8], d_in[9], d_in[10],
                                       neighbits, rowAgg);
  k_final<<<BB, 256, 0, stream>>>(d_in[0], rowAgg, d_in[11], d_in[12],
                                  d_in[13], d_in[14], out);
}

// Round 12
// 188.064 us; speedup vs baseline: 1.6593x; 1.0139x over previous
//
#include <hip/hip_runtime.h>
#include <hip/hip_bf16.h>

#define BB 16
#define NN 1024
#define DD 5
#define RH 8

typedef unsigned long long u64;
typedef unsigned int u32;
typedef __hip_bfloat16 bf16;

static __device__ __forceinline__ float tof(bf16 x) { return __bfloat162float(x); }
// runtime-dtype load: f32 storage if f==true else bf16
static __device__ __forceinline__ float ldf(const void* p, long long i, bool f) {
  return f ? ((const float*)p)[i] : tof(((const bf16*)p)[i]);
}

#define LOG2E 1.4426950408889634f
#define PACK_BLOCKS (BB * NN * 16 / 256)  // 1024
#define KV_BLOCKS (BB * NN / 256)         // 64

// ---------------------------------------------------------------- pack + kv
// Blocks [0, PACK_BLOCKS): pack adjacency into bitsets (storage mode probed
// per-block over the first 4096 words — same data+rule => consistent).
// Blocks [PACK_BLOCKS, PACK_BLOCKS+KV_BLOCKS): precompute per-node packed
// records kvg[node*3+{0,1,2}] = [k0..k3 | k4,v0..v2 | v3,v4,cx,cy], czg[node],
// so k_attn's staging is a pure coalesced copy (k/v' were being recomputed
// 128x per node in k_attn's prologue). First kv block publishes the feats
// dtype flag for k_attn/k_final.
__global__ __launch_bounds__(256) void k_pack(
    const void* __restrict__ adj, const void* __restrict__ feats,
    const void* __restrict__ coors,
    const void* __restrict__ Wk, const void* __restrict__ Wv,
    const void* __restrict__ Wo,
    u64* __restrict__ adjbits, float4* __restrict__ kvg,
    float* __restrict__ czg, int* __restrict__ gflags) {
  __shared__ int sNon01, sNonpair, sLow3;
  __shared__ int sCnt[4];
  __shared__ float wkL[25], wvL[25], woL[25];
  int tid = threadIdx.x;

  if (blockIdx.x >= PACK_BLOCKS) {
    // ---------------- kv precompute role ----------------
    int kb = blockIdx.x - PACK_BLOCKS;
    {
      u32 x = ((const u32*)feats)[tid];
      u32 lo = x & 0xFFFFu;
      int e = (int)((lo >> 7) & 0xFFu);
      bool insane = !(lo == 0u || (e >= 90 && e <= 150));
      u64 m = __ballot(insane);
      if ((tid & 63) == 0) sCnt[tid >> 6] = (int)__popcll(m);
    }
    if (tid < 25) {
      // dtype not known yet; loaded after sync below
    }
    __syncthreads();
    bool f32 = (sCnt[0] + sCnt[1] + sCnt[2] + sCnt[3]) > 64;
    if (tid < 25) {
      wkL[tid] = ldf(Wk, tid, f32);
      wvL[tid] = ldf(Wv, tid, f32);
      woL[tid] = ldf(Wo, tid, f32);
    }
    if (kb == 0 && tid == 0) gflags[0] = f32 ? 1 : 0;
    __syncthreads();
    long long node = (long long)kb * 256 + tid;  // < BB*NN
    float f0 = ldf(feats, node * DD + 0, f32), f1 = ldf(feats, node * DD + 1, f32),
          f2 = ldf(feats, node * DD + 2, f32), f3 = ldf(feats, node * DD + 3, f32),
          f4 = ldf(feats, node * DD + 4, f32);
    float k[DD], tv[DD], v[DD];
    #pragma unroll
    for (int e = 0; e < DD; ++e) {
      k[e] = f0 * wkL[e] + f1 * wkL[5 + e] + f2 * wkL[10 + e] + f3 * wkL[15 + e] +
             f4 * wkL[20 + e];
      tv[e] = f0 * wvL[e] + f1 * wvL[5 + e] + f2 * wvL[10 + e] + f3 * wvL[15 + e] +
              f4 * wvL[20 + e];
    }
    #pragma unroll
    for (int e = 0; e < DD; ++e)
      v[e] = tv[0] * woL[e] + tv[1] * woL[5 + e] + tv[2] * woL[10 + e] +
             tv[3] * woL[15 + e] + tv[4] * woL[20 + e];
    float cx = ldf(coors, node * 3 + 0, f32);
    float cy = ldf(coors, node * 3 + 1, f32);
    float cz = ldf(coors, node * 3 + 2, f32);
    kvg[node * 3 + 0] = make_float4(k[0], k[1], k[2], k[3]);
    kvg[node * 3 + 1] = make_float4(k[4], v[0], v[1], v[2]);
    kvg[node * 3 + 2] = make_float4(v[3], v[4], cx, cy);
    czg[node] = cz;
    return;
  }

  // ---------------- adjacency pack role ----------------
  if (tid == 0) { sNon01 = 0; sNonpair = 0; sLow3 = 0; }
  __syncthreads();
  {
    const u32* aw = (const u32*)adj;
    int non01 = 0, nonpair = 0, low3 = 0;
    for (int i = tid; i < 4096; i += 256) {
      u32 x = aw[i];
      u32 lo = x & 0xFFFFu, hi = x >> 16;
      non01 |= (x > 1u);
      nonpair |= !((lo == 0u || lo == 0x3F80u) && (hi == 0u || hi == 0x3F80u));
      low3 |= (lo == 0x3F80u);
    }
    if (non01) atomicOr(&sNon01, 1);
    if (nonpair) atomicOr(&sNonpair, 1);
    if (low3) atomicOr(&sLow3, 1);
  }
  __syncthreads();
  // mode: 0=int32, 1=byte, 2=bf16, 3=f32
  int mode;
  if (!sNon01) mode = 0;
  else if (!sNonpair) mode = sLow3 ? 2 : 3;
  else mode = 1;

  int gid = blockIdx.x * 256 + tid;
  int w = gid & 15;
  long long row = gid >> 4;
  long long base = row * NN + (long long)w * 64;
  u64 bits = 0;
  if (mode == 3) {
    const uint4* p = (const uint4*)((const float*)adj + base);
    #pragma unroll
    for (int t = 0; t < 16; ++t) {
      uint4 x = p[t];
      if (x.x << 1) bits |= 1ull << (4 * t + 0);   // ignore -0.0
      if (x.y << 1) bits |= 1ull << (4 * t + 1);
      if (x.z << 1) bits |= 1ull << (4 * t + 2);
      if (x.w << 1) bits |= 1ull << (4 * t + 3);
    }
  } else if (mode == 0) {
    const uint4* p = (const uint4*)((const u32*)adj + base);
    #pragma unroll
    for (int t = 0; t < 16; ++t) {
      uint4 x = p[t];
      if (x.x) bits |= 1ull << (4 * t + 0);
      if (x.y) bits |= 1ull << (4 * t + 1);
      if (x.z) bits |= 1ull << (4 * t + 2);
      if (x.w) bits |= 1ull << (4 * t + 3);
    }
  } else if (mode == 2) {
    const uint4* p = (const uint4*)((const unsigned short*)adj + base);
    #pragma unroll
    for (int t = 0; t < 8; ++t) {
      uint4 x = p[t];
      u32 c[4] = {x.x, x.y, x.z, x.w};
      #pragma unroll
      for (int q = 0; q < 4; ++q) {
        if ((c[q] & 0x7FFFu)) bits |= 1ull << (8 * t + 2 * q + 0);
        if ((c[q] >> 16) & 0x7FFFu) bits |= 1ull << (8 * t + 2 * q + 1);
      }
    }
  } else {
    const uint4* p = (const uint4*)((const unsigned char*)adj + base);
    #pragma unroll
    for (int t = 0; t < 4; ++t) {
      uint4 x = p[t];
      u32 c[4] = {x.x, x.y, x.z, x.w};
      #pragma unroll
      for (int q = 0; q < 4; ++q)
        #pragma unroll
        for (int bb = 0; bb < 4; ++bb)
          if ((c[q] >> (8 * bb)) & 0xFFu) bits |= 1ull << (16 * t + 4 * q + bb);
    }
  }
  adjbits[gid] = bits;
}

// -------------------------------------------------------------- two-hop
__global__ __launch_bounds__(256) void k_twohop(const u64* __restrict__ adjbits,
                                                u64* __restrict__ neighbits) {
  __shared__ unsigned short listL[4][NN];
  int wave = threadIdx.x >> 6, lane = threadIdx.x & 63;
  int row = blockIdx.x * 4 + wave;
  int b = row >> 10;
  int i = row & (NN - 1);
  int w = lane & 15;
  const u64* rowp = adjbits + (size_t)row * 16;
  u64 rw = rowp[w];
  unsigned short* list = listL[wave];
  int cnt = 0;
  #pragma unroll
  for (int sw = 0; sw < 16; ++sw) {
    u64 bits = __shfl(rw, sw, 64);
    int mybit = (int)((bits >> lane) & 1ull);
    int pre = __popcll(bits & ((1ull << lane) - 1ull));
    if (mybit) list[cnt + pre] = (unsigned short)(sw * 64 + lane);
    cnt += __popcll(bits);
  }
  __syncthreads();
  u64 acc = rw;
  if (w == (i >> 6)) acc |= 1ull << (i & 63);
  int g = lane >> 4;
  const u64* basep = adjbits + (size_t)b * NN * 16;
  for (int n = g; n < cnt; n += 4) {
    int j = list[n];
    acc |= basep[(size_t)j * 16 + w];
  }
  acc |= __shfl_xor(acc, 16, 64);
  acc |= __shfl_xor(acc, 32, 64);
  if (lane < 16) neighbits[(size_t)row * 16 + lane] = acc;
}

// ------------------------------------------------------------- attention
// r11 structure frozen (proven 42 us): block = (b, chunk of 16 rows, j-half
// of 512), 4 waves x 4 rows, in-loop wave-uniform mask loads, NO it-loop
// unroll, NO min-waves bound. r12 delta: staging is a pure coalesced copy
// from the precomputed kvg/czg records (no per-block k/v' recompute, no
// strided scalar loads); dtype flag read from gflags (no per-block probe).
__global__ __launch_bounds__(256) void k_attn(
    const void* __restrict__ feats, const void* __restrict__ coors,
    const void* __restrict__ Wq,
    const void* __restrict__ wr1, const void* __restrict__ br1,
    const void* __restrict__ wr2, const void* __restrict__ br2,
    const float4* __restrict__ kvg, const float* __restrict__ czg,
    const int* __restrict__ gflags,
    const u64* __restrict__ neighbits, float* __restrict__ rowAgg) {
  __shared__ __align__(16) float4 kvL[512 * 3];  // 24 KB
  __shared__ float czL[512];                     // 2 KB
  __shared__ float wqL[25];
  __shared__ float qL[16 * DD], ciL[16 * 3];
  __shared__ float wrL[3][RH];
  __shared__ float sConst[2];  // [0]=C*log2e, [1]=br2*log2e (when fast)
  __shared__ int sFast;
  int bi = blockIdx.x;
  int b = bi >> 7, rem = bi & 127, chunk = rem >> 1, half = rem & 1;
  int j0 = half * 512;
  int tid = threadIdx.x;
  bool f32 = gflags[0] != 0;
  if (tid < 25) wqL[tid] = ldf(Wq, tid, f32);
  if (tid >= 64 && tid < 64 + RH) {
    int h = tid - 64;
    wrL[0][h] = ldf(wr1, h, f32);
    wrL[1][h] = ldf(br1, h, f32);
    wrL[2][h] = ldf(wr2, h, f32);
  }
  if (tid == 96) {
    float c = 0.0f;
    int ok = 1;
    #pragma unroll
    for (int h = 0; h < RH; ++h) {
      float w1h = ldf(wr1, h, f32);
      if (ldf(br1, h, f32) != 0.0f) ok = 0;
      if (w1h > 0.0f) c += w1h * ldf(wr2, h, f32);
    }
    sConst[0] = c * LOG2E;
    sConst[1] = ldf(br2, 0, f32) * LOG2E;
    sFast = ok;
  }
  // stage kv records + cz for this j-half: pure coalesced copy
  {
    const float4* src = kvg + ((size_t)(b * NN) + j0) * 3;
    for (int idx = tid; idx < 512 * 3; idx += 256) kvL[idx] = src[idx];
    const float* csrc = czg + (size_t)(b * NN) + j0;
    for (int idx = tid; idx < 512; idx += 256) czL[idx] = csrc[idx];
  }
  __syncthreads();
  int fast = sFast;
  // q (scaled by 1/sqrt(5), and log2e when fast) + ci for this chunk's rows
  if (tid < 16) {
    long long row = (long long)b * NN + chunk * 16 + tid;
    float f0 = ldf(feats, row * DD + 0, f32), f1 = ldf(feats, row * DD + 1, f32),
          f2 = ldf(feats, row * DD + 2, f32), f3 = ldf(feats, row * DD + 3, f32),
          f4 = ldf(feats, row * DD + 4, f32);
    float qsc = fast ? (0.4472135954999579f * LOG2E) : 0.4472135954999579f;
    #pragma unroll
    for (int e = 0; e < DD; ++e)
      qL[tid * DD + e] = (f0 * wqL[e] + f1 * wqL[5 + e] + f2 * wqL[10 + e] +
                          f3 * wqL[15 + e] + f4 * wqL[20 + e]) * qsc;
    #pragma unroll
    for (int c = 0; c < 3; ++c)
      ciL[tid * 3 + c] = ldf(coors, row * 3 + c, f32);
  }
  __syncthreads();

  int g = tid >> 6, lane = tid & 63;
  int i0 = chunk * 16 + g * 4;
  float q[4][DD], ci[4][3], l[4], A[4][DD];
  #pragma unroll
  for (int r = 0; r < 4; ++r) {
    #pragma unroll
    for (int e = 0; e < DD; ++e) q[r][e] = qL[(g * 4 + r) * DD + e];
    #pragma unroll
    for (int c = 0; c < 3; ++c) ci[r][c] = ciL[(g * 4 + r) * 3 + c];
    l[r] = 0.0f;
    #pragma unroll
    for (int e = 0; e < DD; ++e) A[r][e] = 0.0f;
  }
  const u64* nb = neighbits + ((size_t)(b * NN + i0)) * 16 + half * 8;
  float Cf = sConst[0], br2f = sConst[1];
  for (int it = 0; it < 8; ++it) {
    int j = it * 64 + lane;
    float4 ka = kvL[j * 3 + 0];
    float4 kb = kvL[j * 3 + 1];
    float4 kc = kvL[j * 3 + 2];
    float jx = kc.z, jy = kc.w, jz = czL[j];
    u64 nw[4];
    #pragma unroll
    for (int r = 0; r < 4; ++r) nw[r] = nb[(size_t)r * 16 + it];
    if (fast) {
      #pragma unroll
      for (int r = 0; r < 4; ++r) {
        float cx = jx - ci[r][0], cy = jy - ci[r][1], cz = jz - ci[r][2];
        float dist =
            __builtin_amdgcn_sqrtf(fmaf(cx, cx, fmaf(cy, cy, fmaf(cz, cz, 1e-8f))));
        float s = fmaf(q[r][0], ka.x, br2f);
        s = fmaf(q[r][1], ka.y, s);
        s = fmaf(q[r][2], ka.z, s);
        s = fmaf(q[r][3], ka.w, s);
        s = fmaf(q[r][4], kb.x, s);
        s = fmaf(Cf, dist, s);
        s = fminf(s, 126.0f);
        s = ((nw[r] >> lane) & 1ull) ? s : -150.0f;
        float p = __builtin_amdgcn_exp2f(s);
        l[r] += p;
        A[r][0] = fmaf(p, kb.y, A[r][0]);
        A[r][1] = fmaf(p, kb.z, A[r][1]);
        A[r][2] = fmaf(p, kb.w, A[r][2]);
        A[r][3] = fmaf(p, kc.x, A[r][3]);
        A[r][4] = fmaf(p, kc.y, A[r][4]);
      }
    } else {
      #pragma unroll
      for (int r = 0; r < 4; ++r) {
        float cx = jx - ci[r][0], cy = jy - ci[r][1], cz = jz - ci[r][2];
        float dist = sqrtf(fmaf(cx, cx, fmaf(cy, cy, fmaf(cz, cz, 1e-8f))));
        float rb = ldf(br2, 0, f32);
        #pragma unroll
        for (int h = 0; h < RH; ++h)
          rb += fmaxf(dist * wrL[0][h] + wrL[1][h], 0.0f) * wrL[2][h];
        float s = fmaf(q[r][0], ka.x, rb);
        s = fmaf(q[r][1], ka.y, s);
        s = fmaf(q[r][2], ka.z, s);
        s = fmaf(q[r][3], ka.w, s);
        s = fmaf(q[r][4], kb.x, s);
        s = fminf(s, 85.0f);
        s = ((nw[r] >> lane) & 1ull) ? s : -100.0f;
        float p = __expf(s);
        l[r] += p;
        A[r][0] = fmaf(p, kb.y, A[r][0]);
        A[r][1] = fmaf(p, kb.z, A[r][1]);
        A[r][2] = fmaf(p, kb.w, A[r][2]);
        A[r][3] = fmaf(p, kc.x, A[r][3]);
        A[r][4] = fmaf(p, kc.y, A[r][4]);
      }
    }
  }
  #pragma unroll
  for (int msk = 1; msk < 64; msk <<= 1) {
    #pragma unroll
    for (int r = 0; r < 4; ++r) {
      l[r] += __shfl_xor(l[r], msk, 64);
      A[r][0] += __shfl_xor(A[r][0], msk, 64);
      A[r][1] += __shfl_xor(A[r][1], msk, 64);
      A[r][2] += __shfl_xor(A[r][2], msk, 64);
      A[r][3] += __shfl_xor(A[r][3], msk, 64);
      A[r][4] += __shfl_xor(A[r][4], msk, 64);
    }
  }
  if (lane == 0) {
    #pragma unroll
    for (int r = 0; r < 4; ++r) {
      float* o = rowAgg + (((size_t)(b * NN + i0 + r)) * 2 + half) * 6;
      o[0] = l[r];
      o[1] = A[r][0]; o[2] = A[r][1]; o[3] = A[r][2]; o[4] = A[r][3]; o[5] = A[r][4];
    }
  }
}

// --------------------------------------------------- finalize: pool + MLP
__global__ __launch_bounds__(256) void k_final(
    const void* __restrict__ feats, const float* __restrict__ rowAgg,
    const int* __restrict__ gflags,
    const void* __restrict__ w1, const void* __restrict__ b1,
    const void* __restrict__ w2, const void* __restrict__ b2,
    float* __restrict__ out) {
  __shared__ float waveL[4][DD];
  __shared__ float poolL[DD];
  __shared__ float hL[128];
  int b = blockIdx.x, tid = threadIdx.x;
  bool f32 = gflags[0] != 0;
  float pe[DD] = {0.f, 0.f, 0.f, 0.f, 0.f};
  for (int n = tid; n < NN; n += 256) {
    const float* ag = rowAgg + ((size_t)(b * NN + n)) * 12;
    float l = ag[0] + ag[6];
    float inv = (l > 0.f) ? 1.0f / l : 0.0f;
    long long base = ((long long)b * NN + n) * DD;
    #pragma unroll
    for (int e = 0; e < DD; ++e)
      pe[e] += ldf(feats, base + e, f32) + (ag[1 + e] + ag[7 + e]) * inv;
  }
  #pragma unroll
  for (int off = 32; off >= 1; off >>= 1)
    #pragma unroll
    for (int e = 0; e < DD; ++e) pe[e] += __shfl_down(pe[e], off, 64);
  int wave = tid >> 6, lane = tid & 63;
  if (lane == 0)
    #pragma unroll
    for (int e = 0; e < DD; ++e) waveL[wave][e] = pe[e];
  __syncthreads();
  if (tid < DD)
    poolL[tid] = (waveL[0][tid] + waveL[1][tid] + waveL[2][tid] + waveL[3][tid]) *
                 (1.0f / 1024.0f);
  __syncthreads();
  if (tid < 128) {
    float acc = ldf(b1, tid, f32);
    #pragma unroll
    for (int d = 0; d < DD; ++d)
      acc = fmaf(poolL[d], ldf(w1, d * 128 + tid, f32), acc);
    hL[tid] = fmaxf(acc, 0.0f);
  }
  __syncthreads();
  if (tid < 3) {
    float s = ldf(b2, tid, f32);
    for (int j = 0; j < 128; ++j) s = fmaf(hL[j], ldf(w2, j * 3 + tid, f32), s);
    out[b * 3 + tid] = s;
  }
}

// ---------------------------------------------------------------- launch
extern "C" void kernel_launch(void* const* d_in, const int* in_sizes, int n_in,
                              void* d_out, int out_size, void* d_ws, size_t ws_size,
                              hipStream_t stream) {
  const void* adj = d_in[2];
  float* out = (float*)d_out;

  char* w = (char*)d_ws;
  int* gflags = (int*)w;                                   // 16 B
  const size_t MB2 = (size_t)BB * NN * 16 * sizeof(u64);   // 2 MiB
  u64* adjbits = (u64*)(w + 512);
  u64* neighbits = (u64*)(w + 512 + MB2);
  float* rowAgg = (float*)(w + 512 + 2 * MB2);             // 768 KiB
  float4* kvg = (float4*)(w + 512 + 2 * MB2 + 786432);     // 768 KiB
  float* czg = (float*)(w + 512 + 2 * MB2 + 2 * 786432);   // 64 KiB

  k_pack<<<PACK_BLOCKS + KV_BLOCKS, 256, 0, stream>>>(
      adj, d_in[0], d_in[1], d_in[4], d_in[5], d_in[6], adjbits, kvg, czg, gflags);
  k_twohop<<<BB * NN / 4, 256, 0, stream>>>(adjbits, neighbits);
  k_attn<<<BB * 128, 256, 0, stream>>>(d_in[0], d_in[1], d_in[3], d_in[7], d_in[8],
                                       d_in[9], d_in[10], kvg, czg, gflags,
                                       neighbits, rowAgg);
  k_final<<<BB, 256, 0, stream>>>(d_in[0], rowAgg, gflags, d_in[11], d_in[12],
                                  d_in[13], d_in[14], out);
}